// Round 4
// baseline (1347.845 us; speedup 1.0000x reference)
//
#include <hip/hip_runtime.h>
#include <hip/hip_bf16.h>
#include <stdint.h>

// N=50000, E=800000, D=128, H=256, G=64
#define HDIM 256
#define NGRAPH 64

#if defined(__has_builtin)
#if __has_builtin(__builtin_amdgcn_mfma_f32_16x16x32_bf16)
#define HAVE_MFMA 1
#endif
#endif

typedef short s16x8 __attribute__((ext_vector_type(8)));   // 8 bf16 as raw shorts (guide §3 form)
typedef float f32x4 __attribute__((ext_vector_type(4)));

__device__ __forceinline__ float bf2f(unsigned short u){
    union { unsigned int i; float f; } x; x.i = ((unsigned int)u) << 16; return x.f;
}
__device__ __forceinline__ unsigned short f2bf(float f){
    union { float f; unsigned int i; } x; x.f = f;
    unsigned int r = x.i + 0x7fffu + ((x.i >> 16) & 1u);
    return (unsigned short)(r >> 16);
}
// dual-dtype scalar load: f32 flag chooses float32 vs bf16 interpretation
__device__ __forceinline__ float ldf(const void* p, int i, int f32){
    return f32 ? ((const float*)p)[i] : bf2f(((const unsigned short*)p)[i]);
}

// ---------------- runtime dtype detection ----------------
// flags[0]=x_is_f32, flags[1]=ei_is_i64, flags[2]=batch_is_i64
__global__ void detect_kernel(const unsigned short* __restrict__ x,
                              const int* __restrict__ ei, const int* __restrict__ batch,
                              int E, int N, int* __restrict__ flags){
    if (threadIdx.x == 0 && blockIdx.x == 0){
        int c = 0;
        for (int i = 0; i < 128; i++){
            unsigned e = (x[2 * i] >> 7) & 0xFFu;   // exponent field of even uint16s
            if (e >= 100u && e <= 140u) c++;
        }
        flags[0] = (c < 96) ? 1 : 0;                // bf16 data -> ~128 pass; f32 low-halves -> ~20
        // int64 edge_index: odd int32 slots (high halves) within first 8E bytes are all zero
        int z = (ei[2*E - 1] == 0) && (ei[2*E - 3] == 0) && (ei[2*E - 5] == 0) && (ei[2*E - 7] == 0);
        flags[1] = z ? 1 : 0;
        // int64 batch: int32 slot N-1 (odd) is a high half (0) if i64; last element (>0) if i32
        flags[2] = (batch[N - 1] == 0) ? 1 : 0;
    }
}

// ---------------- workspace zeroing ----------------
__global__ void zero_kernel(int* __restrict__ p, int n){
    int i = blockIdx.x * 256 + threadIdx.x;
    if (i < n) p[i] = 0;
}

// ---------------- canonical conversion of x ----------------
__global__ void cvt_kernel(const void* __restrict__ src, unsigned short* __restrict__ dst,
                           int n, const int* __restrict__ flags){
    int i = blockIdx.x * 256 + threadIdx.x;
    if (i < n){
        int f32 = flags[0];
        dst[i] = f32 ? f2bf(((const float*)src)[i]) : ((const unsigned short*)src)[i];
    }
}

// ---------------- CSR build (dual int width, guarded) ----------------
__global__ void hist_kernel(const int* __restrict__ ei, int E, int N,
                            const int* __restrict__ flags, int* __restrict__ deg){
    int e = blockIdx.x * 256 + threadIdx.x;
    if (e < E){
        int is64 = flags[1];
        int d = is64 ? ei[2 * E + 2 * e] : ei[E + e];   // dst row
        if ((unsigned)d < (unsigned)N) atomicAdd(&deg[d], 1);
    }
}

__global__ void scan1_kernel(const int* __restrict__ deg, int N,
                             int* __restrict__ incl, int* __restrict__ bsums){
    __shared__ int sm[256];
    int t = threadIdx.x;
    int i = blockIdx.x * 256 + t;
    int v = (i < N) ? deg[i] : 0;
    sm[t] = v; __syncthreads();
    for (int off = 1; off < 256; off <<= 1){
        int tv = (t >= off) ? sm[t - off] : 0;
        __syncthreads();
        sm[t] += tv;
        __syncthreads();
    }
    if (i < N) incl[i] = sm[t];
    if (t == 255) bsums[blockIdx.x] = sm[255];
}

__global__ void scan2_kernel(int* __restrict__ bsums, int nb){
    __shared__ int sm[256];
    int t = threadIdx.x;
    int v = (t < nb) ? bsums[t] : 0;
    sm[t] = v; __syncthreads();
    for (int off = 1; off < 256; off <<= 1){
        int tv = (t >= off) ? sm[t - off] : 0;
        __syncthreads();
        sm[t] += tv;
        __syncthreads();
    }
    if (t < nb) bsums[t] = sm[t] - v;  // exclusive
}

__global__ void scan3_kernel(const int* __restrict__ deg, int N, int E,
                             int* __restrict__ rowptr, const int* __restrict__ bsums){
    int i = blockIdx.x * 256 + threadIdx.x;
    if (i < N) rowptr[i] = rowptr[i] - deg[i] + bsums[blockIdx.x];  // incl -> excl
    if (i == 0) rowptr[N] = E;
}

__global__ void fill_kernel(const int* __restrict__ ei, int E, int N,
                            const int* __restrict__ flags,
                            const int* __restrict__ rowptr, int* __restrict__ fillc,
                            int* __restrict__ csr){
    int e = blockIdx.x * 256 + threadIdx.x;
    if (e < E){
        int is64 = flags[1];
        int d = is64 ? ei[2 * E + 2 * e] : ei[E + e];
        int s = is64 ? ei[2 * e]         : ei[e];
        if ((unsigned)d < (unsigned)N){
            int p = atomicAdd(&fillc[d], 1);
            csr[rowptr[d] + p] = s;
        }
    }
}

// ---------------- weight transpose to canonical bf16: Wt[n*K+k] = W[k*NC+n] ----------------
__global__ void transpose_kernel(const void* __restrict__ W, unsigned short* __restrict__ Wt,
                                 int K, int NC, const int* __restrict__ flags){
    int idx = blockIdx.x * 256 + threadIdx.x;
    if (idx < K * NC){
        int f32 = flags[0];
        int n = idx / K, k = idx - n * K;
        float v = ldf(W, k * NC + n, f32);
        Wt[idx] = f2bf(v);
    }
}

// ---------------- aggregation: Y[i] = feat[i] + sum_{s in CSR[i]} feat[s] ----------------
__global__ void agg_kernel(const unsigned short* __restrict__ feat, int ldi,
                           const int* __restrict__ rowptr, const int* __restrict__ csr,
                           unsigned short* __restrict__ Y, int ldo, int N){
    int i = blockIdx.x;
    int c = threadIdx.x;
    float acc = bf2f(feat[(size_t)i * ldi + c]);
    int lo = rowptr[i], hi = rowptr[i + 1];
    for (int e = lo; e < hi; e++){
        int s = csr[e];
        if ((unsigned)s < (unsigned)N) acc += bf2f(feat[(size_t)s * ldi + c]);
    }
    Y[(size_t)i * ldo + c] = f2bf(acc);
}

// ---- in-place GEMM: AC rows (M x K, row stride 256) -> AC = A*Bt^T + bias (M x 256) ----
#ifdef HAVE_MFMA
__global__ __launch_bounds__(256) void gemm_inplace(
    unsigned short* __restrict__ AC, const unsigned short* __restrict__ Bt,
    const void* __restrict__ bias, int M, int K, const int* __restrict__ flags)
{
    __shared__ __align__(16) unsigned short As[128 * 40];
    __shared__ __align__(16) unsigned short Bs[256 * 40];
    const int tid  = threadIdx.x;
    const int m0   = blockIdx.x * 128;
    const int wave = tid >> 6, lane = tid & 63;
    const int wm   = (wave & 1) * 64;
    const int wn   = (wave >> 1) * 128;
    const int quad = lane >> 4, l16 = lane & 15;
    const int f32  = flags[0];

    const f32x4 zero4 = {0.f, 0.f, 0.f, 0.f};
    f32x4 acc[4][8];
    for (int i = 0; i < 4; i++)
        for (int j = 0; j < 8; j++) acc[i][j] = zero4;

    for (int kb = 0; kb < K; kb += 32){
        for (int j = 0; j < 2; j++){
            int c = tid + j * 256;
            int r = c >> 2, cc = (c & 3) * 8;
            int gr = m0 + r;
            uint4 va; va.x = va.y = va.z = va.w = 0u;
            if (gr < M) va = *(const uint4*)&AC[(size_t)gr * HDIM + kb + cc];
            *(uint4*)&As[r * 40 + cc] = va;
        }
        for (int j = 0; j < 4; j++){
            int c = tid + j * 256;
            int n = c >> 2, cc = (c & 3) * 8;
            *(uint4*)&Bs[n * 40 + cc] = *(const uint4*)&Bt[(size_t)n * K + kb + cc];
        }
        __syncthreads();
        s16x8 af[4];
        for (int mt = 0; mt < 4; mt++)
            af[mt] = *(const s16x8*)&As[(wm + mt * 16 + l16) * 40 + quad * 8];
        for (int nt = 0; nt < 8; nt++){
            s16x8 bfr = *(const s16x8*)&Bs[(wn + nt * 16 + l16) * 40 + quad * 8];
            for (int mt = 0; mt < 4; mt++)
                acc[mt][nt] = __builtin_amdgcn_mfma_f32_16x16x32_bf16(af[mt], bfr, acc[mt][nt], 0, 0, 0);
        }
        __syncthreads();
    }
    for (int mt = 0; mt < 4; mt++){
        for (int nt = 0; nt < 8; nt++){
            int gc = wn + nt * 16 + l16;
            float bv = ldf(bias, gc, f32);
            for (int r = 0; r < 4; r++){
                int gr = m0 + wm + mt * 16 + quad * 4 + r;
                if (gr < M) AC[(size_t)gr * HDIM + gc] = f2bf(acc[mt][nt][r] + bv);
            }
        }
    }
}
#else
// VALU fallback: one thread per output element, staged per-row in LDS
__global__ __launch_bounds__(256) void gemm_inplace(
    unsigned short* __restrict__ AC, const unsigned short* __restrict__ Bt,
    const void* __restrict__ bias, int M, int K, const int* __restrict__ flags)
{
    __shared__ float arow[256];
    int r = blockIdx.x;
    int c = threadIdx.x;
    if (r >= M) return;
    if (c < K) arow[c] = bf2f(AC[(size_t)r * HDIM + c]);
    __syncthreads();
    float acc = ldf(bias, c, flags[0]);
    for (int k = 0; k < K; k++) acc += arow[k] * bf2f(Bt[(size_t)c * K + k]);
    __syncthreads();
    AC[(size_t)r * HDIM + c] = f2bf(acc);
}
#endif

// ---------------- BN column stats ----------------
__global__ __launch_bounds__(256) void colstats_kernel(const unsigned short* __restrict__ Hin, int M,
                                                       float* __restrict__ S, float* __restrict__ Q){
    int c  = threadIdx.x;
    int r0 = blockIdx.x * 128;
    int r1 = min(r0 + 128, M);
    float s = 0.f, q = 0.f;
    for (int r = r0; r < r1; r++){
        float v = bf2f(Hin[(size_t)r * HDIM + c]);
        s += v; q += v * v;
    }
    atomicAdd(&S[c], s);
    atomicAdd(&Q[c], q);
}

__global__ void scaleshift_kernel(const float* __restrict__ S, const float* __restrict__ Q,
                                  const void* __restrict__ g, const void* __restrict__ be,
                                  float* __restrict__ scaleB, float* __restrict__ shiftB,
                                  float invM, const int* __restrict__ flags){
    int c = threadIdx.x;
    int f32 = flags[0];
    float m  = S[c] * invM;
    float v  = Q[c] * invM - m * m;
    float sc = ldf(g, c, f32) * rsqrtf(v + 1e-5f);
    scaleB[c] = sc;
    shiftB[c] = ldf(be, c, f32) - m * sc;
}

// ---------------- normalize + NaN-transparent relu (+ residual) ----------------
__global__ void bnrelu_kernel(const unsigned short* __restrict__ Hin,
                              const float* __restrict__ scaleB, const float* __restrict__ shiftB,
                              const unsigned short* __restrict__ res,
                              unsigned short* __restrict__ Out, int total8){
    int idx = blockIdx.x * 256 + threadIdx.x;
    if (idx >= total8) return;
    int base = idx * 8;
    int c = base & (HDIM - 1);
    unsigned short hv[8], rv[8], ov[8];
    *(uint4*)hv = *(const uint4*)&Hin[base];
    if (res) *(uint4*)rv = *(const uint4*)&res[base];
    for (int j = 0; j < 8; j++){
        float v = bf2f(hv[j]) * scaleB[c + j] + shiftB[c + j];
        v = (v < 0.f) ? 0.f : v;               // NaN passes through (diagnosable)
        if (res) v += bf2f(rv[j]);
        ov[j] = f2bf(v);
    }
    *(uint4*)&Out[base] = *(uint4*)ov;
}

// ---------------- pooling (dual int width for batch) ----------------
__global__ __launch_bounds__(256) void pool_kernel(const unsigned short* __restrict__ X,
                                                   const int* __restrict__ batch, int N,
                                                   const int* __restrict__ flags,
                                                   float* __restrict__ pooled){
    __shared__ int slo, shi;
    int g = blockIdx.x;
    int stride = flags[2] ? 2 : 1;
    if (threadIdx.x == 0){
        int lo = 0, hi = N;
        while (lo < hi){ int mid = (lo + hi) >> 1; if (batch[mid * stride] < g) lo = mid + 1; else hi = mid; }
        slo = lo;
        lo = 0; hi = N;
        while (lo < hi){ int mid = (lo + hi) >> 1; if (batch[mid * stride] < g + 1) lo = mid + 1; else hi = mid; }
        shi = lo;
    }
    __syncthreads();
    int c = threadIdx.x;
    float s = 0.f;
    for (int r = slo; r < shi; r++) s += bf2f(X[(size_t)r * HDIM + c]);
    int cnt = shi - slo;
    pooled[g * HDIM + c] = s / (float)max(cnt, 1);
}

// ---------------- FC head (output dtype mirrors input dtype) ----------------
__global__ __launch_bounds__(256) void head_kernel(const float* __restrict__ pooled,
                                                   const void* __restrict__ fcW1,
                                                   const void* __restrict__ fcb1,
                                                   const void* __restrict__ fcW2,
                                                   const void* __restrict__ fcb2,
                                                   void* __restrict__ out,
                                                   const int* __restrict__ flags){
    __shared__ float sp[256];
    __shared__ float red[256];
    int g = blockIdx.x, j = threadIdx.x;
    int f32 = flags[0];
    sp[j] = pooled[g * HDIM + j];
    __syncthreads();
    float acc = ldf(fcb1, j, f32);
    for (int k = 0; k < HDIM; k++) acc += sp[k] * ldf(fcW1, k * HDIM + j, f32);
    acc = (acc < 0.f) ? 0.f : acc;             // NaN-transparent relu
    red[j] = acc * ldf(fcW2, j, f32);
    __syncthreads();
    for (int s = 128; s > 0; s >>= 1){
        if (j < s) red[j] += red[j + s];
        __syncthreads();
    }
    if (j == 0){
        float r = red[0] + ldf(fcb2, 0, f32);
        if (f32) ((float*)out)[g] = r;
        else     ((unsigned short*)out)[g] = f2bf(r);
    }
}

extern "C" void kernel_launch(void* const* d_in, const int* in_sizes, int n_in,
                              void* d_out, int out_size, void* d_ws, size_t ws_size,
                              hipStream_t stream)
{
    const unsigned short* x    = (const unsigned short*)d_in[0];
    const int*            ei   = (const int*)d_in[1];
    const int*            batch= (const int*)d_in[2];
    const void* W1   = d_in[4];
    const void* b1   = d_in[5];
    const void* W2   = d_in[6];
    const void* b2   = d_in[7];
    const void* W3   = d_in[8];
    const void* b3   = d_in[9];
    const void* g1   = d_in[10];
    const void* be1  = d_in[11];
    const void* g2   = d_in[12];
    const void* be2  = d_in[13];
    const void* g3   = d_in[14];
    const void* be3  = d_in[15];
    const void* fcW1 = d_in[16];
    const void* fcb1 = d_in[17];
    const void* fcW2 = d_in[18];
    const void* fcb2 = d_in[19];

    const int N = in_sizes[0] / 128;   // 50000
    const int E = in_sizes[1] / 2;     // 800000
    const int D = 128;

    // ---- workspace layout (~55.5 MB) ----
    char* p = (char*)d_ws;
    int*   deg    = (int*)p;   p += (size_t)N * 4;
    int*   fillc  = (int*)p;   p += (size_t)N * 4;
    float* stats  = (float*)p; p += 6 * 256 * 4;      // S0 Q0 S1 Q1 S2 Q2
    size_t zbytes = (size_t)(p - (char*)d_ws);        // zeroed region
    int*   flags  = (int*)p;   p += 16 * 4;
    int*   bsums  = (int*)p;   p += 256 * 4;
    int*   rowptr = (int*)p;   p += ((size_t)N + 4) * 4;
    int*   csr    = (int*)p;   p += (size_t)E * 4;
    float* scaleB = (float*)p; p += 256 * 4;
    float* shiftB = (float*)p; p += 256 * 4;
    float* pooled = (float*)p; p += NGRAPH * 256 * 4;
    unsigned short* Wt1 = (unsigned short*)p; p += 256 * 128 * 2;
    unsigned short* Wt2 = (unsigned short*)p; p += 256 * 256 * 2;
    unsigned short* Wt3 = (unsigned short*)p; p += 256 * 256 * 2;
    unsigned short* B1  = (unsigned short*)p; p += (size_t)N * HDIM * 2;
    unsigned short* B2  = (unsigned short*)p; p += (size_t)N * HDIM * 2;
    unsigned short* Xc  = B1;                          // alias: Xc dead before B1 born

    float* S0 = stats + 0 * 256; float* Q0 = stats + 1 * 256;
    float* S1 = stats + 2 * 256; float* Q1 = stats + 3 * 256;
    float* S2 = stats + 4 * 256; float* Q2 = stats + 5 * 256;

    const int nbN = (N + 255) / 256;
    const int nbE = (E + 255) / 256;
    const int gM  = (N + 127) / 128;
    const float invM = 1.0f / (float)N;
    const int total8 = N * HDIM / 8;
    const int zn = (int)(zbytes / 4);
    const int nx = N * D;

    detect_kernel<<<1, 64, 0, stream>>>(x, ei, batch, E, N, flags);
    zero_kernel<<<(zn + 255) / 256, 256, 0, stream>>>((int*)d_ws, zn);

    // CSR build
    hist_kernel<<<nbE, 256, 0, stream>>>(ei, E, N, flags, deg);
    scan1_kernel<<<nbN, 256, 0, stream>>>(deg, N, rowptr, bsums);
    scan2_kernel<<<1, 256, 0, stream>>>(bsums, nbN);
    scan3_kernel<<<nbN, 256, 0, stream>>>(deg, N, E, rowptr, bsums);
    fill_kernel<<<nbE, 256, 0, stream>>>(ei, E, N, flags, rowptr, fillc, csr);

    // canonicalize weights + x
    transpose_kernel<<<(128 * 256) / 256, 256, 0, stream>>>(W1, Wt1, 128, 256, flags);
    transpose_kernel<<<(256 * 256) / 256, 256, 0, stream>>>(W2, Wt2, 256, 256, flags);
    transpose_kernel<<<(256 * 256) / 256, 256, 0, stream>>>(W3, Wt3, 256, 256, flags);
    cvt_kernel<<<(nx + 255) / 256, 256, 0, stream>>>(x, Xc, nx, flags);

    // ---- Layer 1 ----
    agg_kernel<<<N, D, 0, stream>>>(Xc, D, rowptr, csr, B2, HDIM, N);
    gemm_inplace<<<gM, 256, 0, stream>>>(B2, Wt1, b1, N, D, flags);
    colstats_kernel<<<gM, 256, 0, stream>>>(B2, N, S0, Q0);
    scaleshift_kernel<<<1, 256, 0, stream>>>(S0, Q0, g1, be1, scaleB, shiftB, invM, flags);
    bnrelu_kernel<<<(total8 + 255) / 256, 256, 0, stream>>>(
        B2, scaleB, shiftB, (const unsigned short*)nullptr, B1, total8);

    // ---- Layer 2 ----
    agg_kernel<<<N, HDIM, 0, stream>>>(B1, HDIM, rowptr, csr, B2, HDIM, N);
    gemm_inplace<<<gM, 256, 0, stream>>>(B2, Wt2, b2, N, HDIM, flags);
    colstats_kernel<<<gM, 256, 0, stream>>>(B2, N, S1, Q1);
    scaleshift_kernel<<<1, 256, 0, stream>>>(S1, Q1, g2, be2, scaleB, shiftB, invM, flags);
    bnrelu_kernel<<<(total8 + 255) / 256, 256, 0, stream>>>(
        B2, scaleB, shiftB, B1, B1, total8);

    // ---- Layer 3 ----
    agg_kernel<<<N, HDIM, 0, stream>>>(B1, HDIM, rowptr, csr, B2, HDIM, N);
    gemm_inplace<<<gM, 256, 0, stream>>>(B2, Wt3, b3, N, HDIM, flags);
    colstats_kernel<<<gM, 256, 0, stream>>>(B2, N, S2, Q2);
    scaleshift_kernel<<<1, 256, 0, stream>>>(S2, Q2, g3, be3, scaleB, shiftB, invM, flags);
    bnrelu_kernel<<<(total8 + 255) / 256, 256, 0, stream>>>(
        B2, scaleB, shiftB, B1, B1, total8);

    // ---- Pool + head ----
    pool_kernel<<<NGRAPH, 256, 0, stream>>>(B1, batch, N, flags, pooled);
    head_kernel<<<NGRAPH, 256, 0, stream>>>(pooled, fcW1, fcb1, fcW2, fcb2, d_out, flags);

    (void)n_in; (void)out_size; (void)ws_size;
}

// Round 5
// 679.218 us; speedup vs baseline: 1.9844x; 1.9844x over previous
//
#include <hip/hip_runtime.h>
#include <hip/hip_bf16.h>
#include <stdint.h>

// N=50000, E=800000, D=128, H=256, G=64
#define HDIM 256
#define NGRAPH 64

typedef short s16x8 __attribute__((ext_vector_type(8)));   // 8 bf16 as raw shorts
typedef float f32x4 __attribute__((ext_vector_type(4)));

__device__ __forceinline__ float bf2f(unsigned short u){
    union { unsigned int i; float f; } x; x.i = ((unsigned int)u) << 16; return x.f;
}
__device__ __forceinline__ unsigned short f2bf(float f){
    union { float f; unsigned int i; } x; x.f = f;
    unsigned int r = x.i + 0x7fffu + ((x.i >> 16) & 1u);
    return (unsigned short)(r >> 16);
}
__device__ __forceinline__ float ldf(const void* p, int i, int f32){
    return f32 ? ((const float*)p)[i] : bf2f(((const unsigned short*)p)[i]);
}

// ---------------- runtime dtype detection ----------------
__global__ void detect_kernel(const unsigned short* __restrict__ x,
                              const int* __restrict__ ei, const int* __restrict__ batch,
                              int E, int N, int* __restrict__ flags){
    if (threadIdx.x == 0 && blockIdx.x == 0){
        int c = 0;
        for (int i = 0; i < 128; i++){
            unsigned e = (x[2 * i] >> 7) & 0xFFu;
            if (e >= 100u && e <= 140u) c++;
        }
        flags[0] = (c < 96) ? 1 : 0;   // x is f32
        int z = (ei[2*E - 1] == 0) && (ei[2*E - 3] == 0) && (ei[2*E - 5] == 0) && (ei[2*E - 7] == 0);
        flags[1] = z ? 1 : 0;          // edge_index is i64
        flags[2] = (batch[N - 1] == 0) ? 1 : 0;  // batch is i64
    }
}

__global__ void zero_kernel(int* __restrict__ p, int n){
    int i = blockIdx.x * 256 + threadIdx.x;
    if (i < n) p[i] = 0;
}

__global__ void cvt_kernel(const void* __restrict__ src, unsigned short* __restrict__ dst,
                           int n, const int* __restrict__ flags){
    int i = blockIdx.x * 256 + threadIdx.x;
    if (i < n){
        int f32 = flags[0];
        dst[i] = f32 ? f2bf(((const float*)src)[i]) : ((const unsigned short*)src)[i];
    }
}

// ---------------- CSR build ----------------
__global__ void hist_kernel(const int* __restrict__ ei, int E, int N,
                            const int* __restrict__ flags, int* __restrict__ deg){
    int e = blockIdx.x * 256 + threadIdx.x;
    if (e < E){
        int is64 = flags[1];
        int d = is64 ? ei[2 * E + 2 * e] : ei[E + e];
        if ((unsigned)d < (unsigned)N) atomicAdd(&deg[d], 1);
    }
}

__global__ void scan1_kernel(const int* __restrict__ deg, int N,
                             int* __restrict__ incl, int* __restrict__ bsums){
    __shared__ int sm[256];
    int t = threadIdx.x;
    int i = blockIdx.x * 256 + t;
    int v = (i < N) ? deg[i] : 0;
    sm[t] = v; __syncthreads();
    for (int off = 1; off < 256; off <<= 1){
        int tv = (t >= off) ? sm[t - off] : 0;
        __syncthreads();
        sm[t] += tv;
        __syncthreads();
    }
    if (i < N) incl[i] = sm[t];
    if (t == 255) bsums[blockIdx.x] = sm[255];
}

__global__ void scan2_kernel(int* __restrict__ bsums, int nb){
    __shared__ int sm[256];
    int t = threadIdx.x;
    int v = (t < nb) ? bsums[t] : 0;
    sm[t] = v; __syncthreads();
    for (int off = 1; off < 256; off <<= 1){
        int tv = (t >= off) ? sm[t - off] : 0;
        __syncthreads();
        sm[t] += tv;
        __syncthreads();
    }
    if (t < nb) bsums[t] = sm[t] - v;
}

__global__ void scan3_kernel(const int* __restrict__ deg, int N, int E,
                             int* __restrict__ rowptr, const int* __restrict__ bsums){
    int i = blockIdx.x * 256 + threadIdx.x;
    if (i < N) rowptr[i] = rowptr[i] - deg[i] + bsums[blockIdx.x];
    if (i == 0) rowptr[N] = E;
}

__global__ void fill_kernel(const int* __restrict__ ei, int E, int N,
                            const int* __restrict__ flags,
                            const int* __restrict__ rowptr, int* __restrict__ fillc,
                            int* __restrict__ csr){
    int e = blockIdx.x * 256 + threadIdx.x;
    if (e < E){
        int is64 = flags[1];
        int d = is64 ? ei[2 * E + 2 * e] : ei[E + e];
        int s = is64 ? ei[2 * e]         : ei[e];
        if ((unsigned)d < (unsigned)N){
            int p = atomicAdd(&fillc[d], 1);
            csr[rowptr[d] + p] = s;
        }
    }
}

// ---------------- weight transpose to bf16: Wt[n*K+k] = W[k*NC+n] ----------------
__global__ void transpose_kernel(const void* __restrict__ W, unsigned short* __restrict__ Wt,
                                 int K, int NC, const int* __restrict__ flags){
    int idx = blockIdx.x * 256 + threadIdx.x;
    if (idx < K * NC){
        int f32 = flags[0];
        int n = idx / K, k = idx - n * K;
        Wt[idx] = f2bf(ldf(W, k * NC + n, f32));
    }
}

// ---------------- vectorized aggregation: C/8 lanes per node, uint4 loads ----------------
template<int C>
__global__ __launch_bounds__(256) void agg_vec(const unsigned short* __restrict__ feat, int ldi,
                                               const int* __restrict__ rowptr, const int* __restrict__ csr,
                                               unsigned short* __restrict__ Y, int ldo, int N){
    constexpr int L   = C / 8;      // lanes per node (16 or 32)
    constexpr int NPB = 256 / L;    // nodes per block
    int node = blockIdx.x * NPB + threadIdx.x / L;
    int lane = threadIdx.x & (L - 1);
    if (node >= N) return;
    int c0 = lane * 8;

    unsigned short t0[8];
    *(uint4*)t0 = *(const uint4*)&feat[(size_t)node * ldi + c0];
    float acc[8];
    #pragma unroll
    for (int j = 0; j < 8; j++) acc[j] = bf2f(t0[j]);

    int lo = rowptr[node], hi = rowptr[node + 1];
    int e = lo;
    for (; e + 1 < hi; e += 2){
        int s0 = csr[e], s1 = csr[e + 1];
        uint4 a = *(const uint4*)&feat[(size_t)s0 * ldi + c0];
        uint4 b = *(const uint4*)&feat[(size_t)s1 * ldi + c0];
        unsigned short ta[8], tb[8];
        *(uint4*)ta = a; *(uint4*)tb = b;
        #pragma unroll
        for (int j = 0; j < 8; j++) acc[j] += bf2f(ta[j]) + bf2f(tb[j]);
    }
    if (e < hi){
        int s0 = csr[e];
        unsigned short ta[8];
        *(uint4*)ta = *(const uint4*)&feat[(size_t)s0 * ldi + c0];
        #pragma unroll
        for (int j = 0; j < 8; j++) acc[j] += bf2f(ta[j]);
    }
    unsigned short o[8];
    #pragma unroll
    for (int j = 0; j < 8; j++) o[j] = f2bf(acc[j]);
    *(uint4*)&Y[(size_t)node * ldo + c0] = *(uint4*)o;
}

// ---- in-place GEMM + fused BN column stats ----
// AC rows (M x K, row stride 256) -> AC = A*Bt^T + bias; atomically accumulates col sum/sumsq into S/Q.
__global__ __launch_bounds__(256) void gemm_inplace(
    unsigned short* __restrict__ AC, const unsigned short* __restrict__ Bt,
    const void* __restrict__ bias, int M, int K, const int* __restrict__ flags,
    float* __restrict__ S, float* __restrict__ Q)
{
    __shared__ __align__(16) unsigned short As[128 * 40];
    __shared__ __align__(16) unsigned short Bs[256 * 40];
    __shared__ float sS[256];
    __shared__ float sQ[256];
    const int tid  = threadIdx.x;
    const int m0   = blockIdx.x * 128;
    const int wave = tid >> 6, lane = tid & 63;
    const int wm   = (wave & 1) * 64;
    const int wn   = (wave >> 1) * 128;
    const int quad = lane >> 4, l16 = lane & 15;
    const int f32  = flags[0];

    sS[tid] = 0.f; sQ[tid] = 0.f;

    const f32x4 zero4 = {0.f, 0.f, 0.f, 0.f};
    f32x4 acc[4][8];
    for (int i = 0; i < 4; i++)
        for (int j = 0; j < 8; j++) acc[i][j] = zero4;

    for (int kb = 0; kb < K; kb += 32){
        for (int j = 0; j < 2; j++){
            int c = tid + j * 256;
            int r = c >> 2, cc = (c & 3) * 8;
            int gr = m0 + r;
            uint4 va; va.x = va.y = va.z = va.w = 0u;
            if (gr < M) va = *(const uint4*)&AC[(size_t)gr * HDIM + kb + cc];
            *(uint4*)&As[r * 40 + cc] = va;
        }
        for (int j = 0; j < 4; j++){
            int c = tid + j * 256;
            int n = c >> 2, cc = (c & 3) * 8;
            *(uint4*)&Bs[n * 40 + cc] = *(const uint4*)&Bt[(size_t)n * K + kb + cc];
        }
        __syncthreads();
        s16x8 af[4];
        for (int mt = 0; mt < 4; mt++)
            af[mt] = *(const s16x8*)&As[(wm + mt * 16 + l16) * 40 + quad * 8];
        for (int nt = 0; nt < 8; nt++){
            s16x8 bfr = *(const s16x8*)&Bs[(wn + nt * 16 + l16) * 40 + quad * 8];
            for (int mt = 0; mt < 4; mt++)
                acc[mt][nt] = __builtin_amdgcn_mfma_f32_16x16x32_bf16(af[mt], bfr, acc[mt][nt], 0, 0, 0);
        }
        __syncthreads();
    }
    // epilogue: store + per-column partial stats (C/D layout col=lane&15, row=(lane>>4)*4+reg)
    for (int nt = 0; nt < 8; nt++){
        int gc = wn + nt * 16 + l16;
        float bv = ldf(bias, gc, f32);
        float ps = 0.f, pq = 0.f;
        for (int mt = 0; mt < 4; mt++){
            for (int r = 0; r < 4; r++){
                int gr = m0 + wm + mt * 16 + quad * 4 + r;
                if (gr < M){
                    float val = acc[mt][nt][r] + bv;
                    AC[(size_t)gr * HDIM + gc] = f2bf(val);
                    ps += val; pq += val * val;
                }
            }
        }
        atomicAdd(&sS[gc], ps);
        atomicAdd(&sQ[gc], pq);
    }
    __syncthreads();
    atomicAdd(&S[tid], sS[tid]);
    atomicAdd(&Q[tid], sQ[tid]);
}

__global__ void scaleshift_kernel(const float* __restrict__ S, const float* __restrict__ Q,
                                  const void* __restrict__ g, const void* __restrict__ be,
                                  float* __restrict__ scaleB, float* __restrict__ shiftB,
                                  float invM, const int* __restrict__ flags){
    int c = threadIdx.x;
    int f32 = flags[0];
    float m  = S[c] * invM;
    float v  = Q[c] * invM - m * m;
    float sc = ldf(g, c, f32) * rsqrtf(v + 1e-5f);
    scaleB[c] = sc;
    shiftB[c] = ldf(be, c, f32) - m * sc;
}

// ---------------- normalize + relu (+ residual) ----------------
__global__ void bnrelu_kernel(const unsigned short* __restrict__ Hin,
                              const float* __restrict__ scaleB, const float* __restrict__ shiftB,
                              const unsigned short* __restrict__ res,
                              unsigned short* __restrict__ Out, int total8){
    int idx = blockIdx.x * 256 + threadIdx.x;
    if (idx >= total8) return;
    int base = idx * 8;
    int c = base & (HDIM - 1);
    unsigned short hv[8], rv[8], ov[8];
    *(uint4*)hv = *(const uint4*)&Hin[base];
    if (res) *(uint4*)rv = *(const uint4*)&res[base];
    for (int j = 0; j < 8; j++){
        float v = bf2f(hv[j]) * scaleB[c + j] + shiftB[c + j];
        v = (v < 0.f) ? 0.f : v;
        if (res) v += bf2f(rv[j]);
        ov[j] = f2bf(v);
    }
    *(uint4*)&Out[base] = *(uint4*)ov;
}

// ---------------- pooling phase 1: coalesced run-accumulation over 128-row strips ----------------
__global__ __launch_bounds__(256) void pool_sum_kernel(const unsigned short* __restrict__ X,
                                                       const int* __restrict__ batch, int N,
                                                       const int* __restrict__ flags,
                                                       float* __restrict__ sums){
    int r0 = blockIdx.x * 128;
    int r1 = min(r0 + 128, N);
    if (r0 >= N) return;
    int t = threadIdx.x;            // column
    int stride = flags[2] ? 2 : 1;
    float acc = 0.f;
    int curg = batch[r0 * stride];
    for (int r = r0; r < r1; r++){
        int g = batch[r * stride];
        if (g != curg){
            atomicAdd(&sums[curg * HDIM + t], acc);
            acc = 0.f; curg = g;
        }
        acc += bf2f(X[(size_t)r * HDIM + t]);
    }
    atomicAdd(&sums[curg * HDIM + t], acc);
}

// ---------------- pooling phase 2: divide by count ----------------
__global__ __launch_bounds__(256) void pool_final_kernel(const float* __restrict__ sums,
                                                         const int* __restrict__ batch, int N,
                                                         const int* __restrict__ flags,
                                                         float* __restrict__ pooled){
    __shared__ int slo, shi;
    int g = blockIdx.x;
    int stride = flags[2] ? 2 : 1;
    if (threadIdx.x == 0){
        int lo = 0, hi = N;
        while (lo < hi){ int mid = (lo + hi) >> 1; if (batch[mid * stride] < g) lo = mid + 1; else hi = mid; }
        slo = lo;
        lo = 0; hi = N;
        while (lo < hi){ int mid = (lo + hi) >> 1; if (batch[mid * stride] < g + 1) lo = mid + 1; else hi = mid; }
        shi = lo;
    }
    __syncthreads();
    int c = threadIdx.x;
    int cnt = shi - slo;
    pooled[g * HDIM + c] = sums[g * HDIM + c] / (float)max(cnt, 1);
}

// ---------------- FC head ----------------
__global__ __launch_bounds__(256) void head_kernel(const float* __restrict__ pooled,
                                                   const void* __restrict__ fcW1,
                                                   const void* __restrict__ fcb1,
                                                   const void* __restrict__ fcW2,
                                                   const void* __restrict__ fcb2,
                                                   void* __restrict__ out,
                                                   const int* __restrict__ flags){
    __shared__ float sp[256];
    __shared__ float red[256];
    int g = blockIdx.x, j = threadIdx.x;
    int f32 = flags[0];
    sp[j] = pooled[g * HDIM + j];
    __syncthreads();
    float acc = ldf(fcb1, j, f32);
    for (int k = 0; k < HDIM; k++) acc += sp[k] * ldf(fcW1, k * HDIM + j, f32);
    acc = (acc < 0.f) ? 0.f : acc;
    red[j] = acc * ldf(fcW2, j, f32);
    __syncthreads();
    for (int s = 128; s > 0; s >>= 1){
        if (j < s) red[j] += red[j + s];
        __syncthreads();
    }
    if (j == 0){
        float r = red[0] + ldf(fcb2, 0, f32);
        if (f32) ((float*)out)[g] = r;
        else     ((unsigned short*)out)[g] = f2bf(r);
    }
}

extern "C" void kernel_launch(void* const* d_in, const int* in_sizes, int n_in,
                              void* d_out, int out_size, void* d_ws, size_t ws_size,
                              hipStream_t stream)
{
    const unsigned short* x    = (const unsigned short*)d_in[0];
    const int*            ei   = (const int*)d_in[1];
    const int*            batch= (const int*)d_in[2];
    const void* W1   = d_in[4];
    const void* b1   = d_in[5];
    const void* W2   = d_in[6];
    const void* b2   = d_in[7];
    const void* W3   = d_in[8];
    const void* b3   = d_in[9];
    const void* g1   = d_in[10];
    const void* be1  = d_in[11];
    const void* g2   = d_in[12];
    const void* be2  = d_in[13];
    const void* g3   = d_in[14];
    const void* be3  = d_in[15];
    const void* fcW1 = d_in[16];
    const void* fcb1 = d_in[17];
    const void* fcW2 = d_in[18];
    const void* fcb2 = d_in[19];

    const int N = in_sizes[0] / 128;   // 50000
    const int E = in_sizes[1] / 2;     // 800000
    const int D = 128;

    // ---- workspace layout (~55.6 MB) ----
    char* p = (char*)d_ws;
    int*   deg     = (int*)p;   p += (size_t)N * 4;
    int*   fillc   = (int*)p;   p += (size_t)N * 4;
    float* stats   = (float*)p; p += 6 * 256 * 4;            // S0 Q0 S1 Q1 S2 Q2
    float* poolsum = (float*)p; p += NGRAPH * HDIM * 4;      // zeroed
    size_t zbytes  = (size_t)(p - (char*)d_ws);
    int*   flags   = (int*)p;   p += 16 * 4;
    int*   bsums   = (int*)p;   p += 256 * 4;
    int*   rowptr  = (int*)p;   p += ((size_t)N + 4) * 4;
    int*   csr     = (int*)p;   p += (size_t)E * 4;
    float* scaleB  = (float*)p; p += 256 * 4;
    float* shiftB  = (float*)p; p += 256 * 4;
    float* pooled  = (float*)p; p += NGRAPH * HDIM * 4;
    unsigned short* Wt1 = (unsigned short*)p; p += 256 * 128 * 2;
    unsigned short* Wt2 = (unsigned short*)p; p += 256 * 256 * 2;
    unsigned short* Wt3 = (unsigned short*)p; p += 256 * 256 * 2;
    unsigned short* B1  = (unsigned short*)p; p += (size_t)N * HDIM * 2;
    unsigned short* B2  = (unsigned short*)p; p += (size_t)N * HDIM * 2;
    unsigned short* Xc  = B1;                                // Xc dead before B1 born

    float* S0 = stats + 0 * 256; float* Q0 = stats + 1 * 256;
    float* S1 = stats + 2 * 256; float* Q1 = stats + 3 * 256;
    float* S2 = stats + 4 * 256; float* Q2 = stats + 5 * 256;

    const int nbN = (N + 255) / 256;
    const int nbE = (E + 255) / 256;
    const int gM  = (N + 127) / 128;
    const float invM = 1.0f / (float)N;
    const int total8 = N * HDIM / 8;
    const int zn = (int)(zbytes / 4);
    const int nx = N * D;

    detect_kernel<<<1, 64, 0, stream>>>(x, ei, batch, E, N, flags);
    zero_kernel<<<(zn + 255) / 256, 256, 0, stream>>>((int*)d_ws, zn);

    // CSR build
    hist_kernel<<<nbE, 256, 0, stream>>>(ei, E, N, flags, deg);
    scan1_kernel<<<nbN, 256, 0, stream>>>(deg, N, rowptr, bsums);
    scan2_kernel<<<1, 256, 0, stream>>>(bsums, nbN);
    scan3_kernel<<<nbN, 256, 0, stream>>>(deg, N, E, rowptr, bsums);
    fill_kernel<<<nbE, 256, 0, stream>>>(ei, E, N, flags, rowptr, fillc, csr);

    // canonicalize weights + x
    transpose_kernel<<<(128 * 256) / 256, 256, 0, stream>>>(W1, Wt1, 128, 256, flags);
    transpose_kernel<<<(256 * 256) / 256, 256, 0, stream>>>(W2, Wt2, 256, 256, flags);
    transpose_kernel<<<(256 * 256) / 256, 256, 0, stream>>>(W3, Wt3, 256, 256, flags);
    cvt_kernel<<<(nx + 255) / 256, 256, 0, stream>>>(x, Xc, nx, flags);

    // ---- Layer 1 ----
    agg_vec<128><<<(N + 15) / 16, 256, 0, stream>>>(Xc, D, rowptr, csr, B2, HDIM, N);
    gemm_inplace<<<gM, 256, 0, stream>>>(B2, Wt1, b1, N, D, flags, S0, Q0);
    scaleshift_kernel<<<1, 256, 0, stream>>>(S0, Q0, g1, be1, scaleB, shiftB, invM, flags);
    bnrelu_kernel<<<(total8 + 255) / 256, 256, 0, stream>>>(
        B2, scaleB, shiftB, (const unsigned short*)nullptr, B1, total8);

    // ---- Layer 2 ----
    agg_vec<256><<<(N + 7) / 8, 256, 0, stream>>>(B1, HDIM, rowptr, csr, B2, HDIM, N);
    gemm_inplace<<<gM, 256, 0, stream>>>(B2, Wt2, b2, N, HDIM, flags, S1, Q1);
    scaleshift_kernel<<<1, 256, 0, stream>>>(S1, Q1, g2, be2, scaleB, shiftB, invM, flags);
    bnrelu_kernel<<<(total8 + 255) / 256, 256, 0, stream>>>(
        B2, scaleB, shiftB, B1, B1, total8);

    // ---- Layer 3 ----
    agg_vec<256><<<(N + 7) / 8, 256, 0, stream>>>(B1, HDIM, rowptr, csr, B2, HDIM, N);
    gemm_inplace<<<gM, 256, 0, stream>>>(B2, Wt3, b3, N, HDIM, flags, S2, Q2);
    scaleshift_kernel<<<1, 256, 0, stream>>>(S2, Q2, g3, be3, scaleB, shiftB, invM, flags);
    bnrelu_kernel<<<(total8 + 255) / 256, 256, 0, stream>>>(
        B2, scaleB, shiftB, B1, B1, total8);

    // ---- Pool + head ----
    pool_sum_kernel<<<gM, 256, 0, stream>>>(B1, batch, N, flags, poolsum);
    pool_final_kernel<<<NGRAPH, 256, 0, stream>>>(poolsum, batch, N, flags, pooled);
    head_kernel<<<NGRAPH, 256, 0, stream>>>(pooled, fcW1, fcb1, fcW2, fcb2, d_out, flags);

    (void)n_in; (void)out_size; (void)ws_size;
}

// Round 6
// 654.769 us; speedup vs baseline: 2.0585x; 1.0373x over previous
//
#include <hip/hip_runtime.h>
#include <hip/hip_bf16.h>
#include <stdint.h>

// N=50000, E=800000, D=128, H=256, G=64
#define HDIM 256
#define NGRAPH 64

typedef short s16x8 __attribute__((ext_vector_type(8)));
typedef float f32x4 __attribute__((ext_vector_type(4)));

__device__ __forceinline__ float bf2f(unsigned short u){
    union { unsigned int i; float f; } x; x.i = ((unsigned int)u) << 16; return x.f;
}
__device__ __forceinline__ unsigned short f2bf(float f){
    union { float f; unsigned int i; } x; x.f = f;
    unsigned int r = x.i + 0x7fffu + ((x.i >> 16) & 1u);
    return (unsigned short)(r >> 16);
}
__device__ __forceinline__ float ldf(const void* p, int i, int f32){
    return f32 ? ((const float*)p)[i] : bf2f(((const unsigned short*)p)[i]);
}

// ---------------- runtime dtype detection ----------------
__global__ void detect_kernel(const unsigned short* __restrict__ x,
                              const int* __restrict__ ei, const int* __restrict__ batch,
                              int E, int N, int* __restrict__ flags){
    if (threadIdx.x == 0 && blockIdx.x == 0){
        int c = 0;
        for (int i = 0; i < 128; i++){
            unsigned e = (x[2 * i] >> 7) & 0xFFu;
            if (e >= 100u && e <= 140u) c++;
        }
        flags[0] = (c < 96) ? 1 : 0;   // x is f32
        int z = (ei[2*E - 1] == 0) && (ei[2*E - 3] == 0) && (ei[2*E - 5] == 0) && (ei[2*E - 7] == 0);
        flags[1] = z ? 1 : 0;          // edge_index is i64
        flags[2] = (batch[N - 1] == 0) ? 1 : 0;  // batch is i64
    }
}

__global__ void zero_kernel(int* __restrict__ p, int n){
    int i = blockIdx.x * 256 + threadIdx.x;
    if (i < n) p[i] = 0;
}

__global__ void cvt_kernel(const void* __restrict__ src, unsigned short* __restrict__ dst,
                           int n, const int* __restrict__ flags){
    int i = blockIdx.x * 256 + threadIdx.x;
    if (i < n){
        int f32 = flags[0];
        dst[i] = f32 ? f2bf(((const float*)src)[i]) : ((const unsigned short*)src)[i];
    }
}

// ---------------- CSR build ----------------
__global__ void hist_kernel(const int* __restrict__ ei, int E, int N,
                            const int* __restrict__ flags, int* __restrict__ deg){
    int e = blockIdx.x * 256 + threadIdx.x;
    if (e < E){
        int is64 = flags[1];
        int d = is64 ? ei[2 * E + 2 * e] : ei[E + e];
        if ((unsigned)d < (unsigned)N) atomicAdd(&deg[d], 1);
    }
}

__global__ void scan1_kernel(const int* __restrict__ deg, int N,
                             int* __restrict__ incl, int* __restrict__ bsums){
    __shared__ int sm[256];
    int t = threadIdx.x;
    int i = blockIdx.x * 256 + t;
    int v = (i < N) ? deg[i] : 0;
    sm[t] = v; __syncthreads();
    for (int off = 1; off < 256; off <<= 1){
        int tv = (t >= off) ? sm[t - off] : 0;
        __syncthreads();
        sm[t] += tv;
        __syncthreads();
    }
    if (i < N) incl[i] = sm[t];
    if (t == 255) bsums[blockIdx.x] = sm[255];
}

__global__ void scan2_kernel(int* __restrict__ bsums, int nb){
    __shared__ int sm[256];
    int t = threadIdx.x;
    int v = (t < nb) ? bsums[t] : 0;
    sm[t] = v; __syncthreads();
    for (int off = 1; off < 256; off <<= 1){
        int tv = (t >= off) ? sm[t - off] : 0;
        __syncthreads();
        sm[t] += tv;
        __syncthreads();
    }
    if (t < nb) bsums[t] = sm[t] - v;
}

__global__ void scan3_kernel(const int* __restrict__ deg, int N, int E,
                             int* __restrict__ rowptr, const int* __restrict__ bsums){
    int i = blockIdx.x * 256 + threadIdx.x;
    if (i < N) rowptr[i] = rowptr[i] - deg[i] + bsums[blockIdx.x];
    if (i == 0) rowptr[N] = E;
}

__global__ void fill_kernel(const int* __restrict__ ei, int E, int N,
                            const int* __restrict__ flags,
                            const int* __restrict__ rowptr, int* __restrict__ fillc,
                            int* __restrict__ csr){
    int e = blockIdx.x * 256 + threadIdx.x;
    if (e < E){
        int is64 = flags[1];
        int d = is64 ? ei[2 * E + 2 * e] : ei[E + e];
        int s = is64 ? ei[2 * e]         : ei[e];
        if ((unsigned)d < (unsigned)N){
            int p = atomicAdd(&fillc[d], 1);
            csr[rowptr[d] + p] = s;
        }
    }
}

// ---------------- weight transpose to bf16: Wt[n*K+k] = W[k*NC+n] ----------------
__global__ void transpose_kernel(const void* __restrict__ W, unsigned short* __restrict__ Wt,
                                 int K, int NC, const int* __restrict__ flags){
    int idx = blockIdx.x * 256 + threadIdx.x;
    if (idx < K * NC){
        int f32 = flags[0];
        int n = idx / K, k = idx - n * K;
        Wt[idx] = f2bf(ldf(W, k * NC + n, f32));
    }
}

// ---------------- vectorized aggregation: C/8 lanes per node, unroll-4 uint4 loads ----------------
template<int C>
__global__ __launch_bounds__(256) void agg_vec(const unsigned short* __restrict__ feat, int ldi,
                                               const int* __restrict__ rowptr, const int* __restrict__ csr,
                                               unsigned short* __restrict__ Y, int ldo, int N){
    constexpr int L   = C / 8;      // lanes per node (16 or 32)
    constexpr int NPB = 256 / L;    // nodes per block
    int node = blockIdx.x * NPB + threadIdx.x / L;
    int lane = threadIdx.x & (L - 1);
    if (node >= N) return;
    int c0 = lane * 8;
    const unsigned short* base = feat + c0;

    unsigned short t0[8];
    *(uint4*)t0 = *(const uint4*)&feat[(size_t)node * ldi + c0];
    float acc[8];
    #pragma unroll
    for (int j = 0; j < 8; j++) acc[j] = bf2f(t0[j]);

    int lo = rowptr[node], hi = rowptr[node + 1];
    int e = lo;
    for (; e + 3 < hi; e += 4){
        int s0 = csr[e], s1 = csr[e + 1], s2 = csr[e + 2], s3 = csr[e + 3];
        uint4 va = *(const uint4*)&base[(size_t)s0 * ldi];
        uint4 vb = *(const uint4*)&base[(size_t)s1 * ldi];
        uint4 vc = *(const uint4*)&base[(size_t)s2 * ldi];
        uint4 vd = *(const uint4*)&base[(size_t)s3 * ldi];
        unsigned short ta[8], tb[8], tc[8], td[8];
        *(uint4*)ta = va; *(uint4*)tb = vb; *(uint4*)tc = vc; *(uint4*)td = vd;
        #pragma unroll
        for (int j = 0; j < 8; j++)
            acc[j] += (bf2f(ta[j]) + bf2f(tb[j])) + (bf2f(tc[j]) + bf2f(td[j]));
    }
    for (; e < hi; e++){
        int s0 = csr[e];
        unsigned short ta[8];
        *(uint4*)ta = *(const uint4*)&base[(size_t)s0 * ldi];
        #pragma unroll
        for (int j = 0; j < 8; j++) acc[j] += bf2f(ta[j]);
    }
    unsigned short o[8];
    #pragma unroll
    for (int j = 0; j < 8; j++) o[j] = f2bf(acc[j]);
    *(uint4*)&Y[(size_t)node * ldo + c0] = *(uint4*)o;
}

// ---- in-place GEMM + fused BN column stats ----
__global__ __launch_bounds__(256) void gemm_inplace(
    unsigned short* __restrict__ AC, const unsigned short* __restrict__ Bt,
    const void* __restrict__ bias, int M, int K, const int* __restrict__ flags,
    float* __restrict__ S, float* __restrict__ Q)
{
    __shared__ __align__(16) unsigned short As[128 * 40];
    __shared__ __align__(16) unsigned short Bs[256 * 40];
    __shared__ float sS[256];
    __shared__ float sQ[256];
    const int tid  = threadIdx.x;
    const int m0   = blockIdx.x * 128;
    const int wave = tid >> 6, lane = tid & 63;
    const int wm   = (wave & 1) * 64;
    const int wn   = (wave >> 1) * 128;
    const int quad = lane >> 4, l16 = lane & 15;
    const int f32  = flags[0];

    sS[tid] = 0.f; sQ[tid] = 0.f;

    const f32x4 zero4 = {0.f, 0.f, 0.f, 0.f};
    f32x4 acc[4][8];
    for (int i = 0; i < 4; i++)
        for (int j = 0; j < 8; j++) acc[i][j] = zero4;

    for (int kb = 0; kb < K; kb += 32){
        for (int j = 0; j < 2; j++){
            int c = tid + j * 256;
            int r = c >> 2, cc = (c & 3) * 8;
            int gr = m0 + r;
            uint4 va; va.x = va.y = va.z = va.w = 0u;
            if (gr < M) va = *(const uint4*)&AC[(size_t)gr * HDIM + kb + cc];
            *(uint4*)&As[r * 40 + cc] = va;
        }
        for (int j = 0; j < 4; j++){
            int c = tid + j * 256;
            int n = c >> 2, cc = (c & 3) * 8;
            *(uint4*)&Bs[n * 40 + cc] = *(const uint4*)&Bt[(size_t)n * K + kb + cc];
        }
        __syncthreads();
        s16x8 af[4];
        for (int mt = 0; mt < 4; mt++)
            af[mt] = *(const s16x8*)&As[(wm + mt * 16 + l16) * 40 + quad * 8];
        for (int nt = 0; nt < 8; nt++){
            s16x8 bfr = *(const s16x8*)&Bs[(wn + nt * 16 + l16) * 40 + quad * 8];
            for (int mt = 0; mt < 4; mt++)
                acc[mt][nt] = __builtin_amdgcn_mfma_f32_16x16x32_bf16(af[mt], bfr, acc[mt][nt], 0, 0, 0);
        }
        __syncthreads();
    }
    for (int nt = 0; nt < 8; nt++){
        int gc = wn + nt * 16 + l16;
        float bv = ldf(bias, gc, f32);
        float ps = 0.f, pq = 0.f;
        for (int mt = 0; mt < 4; mt++){
            for (int r = 0; r < 4; r++){
                int gr = m0 + wm + mt * 16 + quad * 4 + r;
                if (gr < M){
                    float val = acc[mt][nt][r] + bv;
                    AC[(size_t)gr * HDIM + gc] = f2bf(val);
                    ps += val; pq += val * val;
                }
            }
        }
        atomicAdd(&sS[gc], ps);
        atomicAdd(&sQ[gc], pq);
    }
    __syncthreads();
    atomicAdd(&S[tid], sS[tid]);
    atomicAdd(&Q[tid], sQ[tid]);
}

// ---------------- bnrelu with inlined scale/shift computation (+ optional residual) ----------------
__global__ void bnrelu_kernel(const unsigned short* __restrict__ Hin,
                              const float* __restrict__ S, const float* __restrict__ Q,
                              const void* __restrict__ g, const void* __restrict__ be,
                              float invM, const int* __restrict__ flags,
                              const unsigned short* __restrict__ res,
                              unsigned short* __restrict__ Out, int total8){
    __shared__ float sscale[256], sshift[256];
    int tid = threadIdx.x;
    {
        int f32 = flags[0];
        float m  = S[tid] * invM;
        float v  = Q[tid] * invM - m * m;
        float sc = ldf(g, tid, f32) * rsqrtf(v + 1e-5f);
        sscale[tid] = sc;
        sshift[tid] = ldf(be, tid, f32) - m * sc;
    }
    __syncthreads();
    int idx = blockIdx.x * 256 + tid;
    if (idx >= total8) return;
    int base = idx * 8;
    int c = base & (HDIM - 1);
    unsigned short hv[8], rv[8], ov[8];
    *(uint4*)hv = *(const uint4*)&Hin[base];
    if (res) *(uint4*)rv = *(const uint4*)&res[base];
    #pragma unroll
    for (int j = 0; j < 8; j++){
        float v = bf2f(hv[j]) * sscale[c + j] + sshift[c + j];
        v = (v < 0.f) ? 0.f : v;
        if (res) v += bf2f(rv[j]);
        ov[j] = f2bf(v);
    }
    *(uint4*)&Out[base] = *(uint4*)ov;
}

// ---------------- layer-3 bnrelu fused with pool partial sums (x3 never materialized) ----------------
__global__ __launch_bounds__(256) void bnrelu_pool_kernel(
    const unsigned short* __restrict__ H, const unsigned short* __restrict__ res,
    const float* __restrict__ S, const float* __restrict__ Q,
    const void* __restrict__ g, const void* __restrict__ be,
    float invM, const int* __restrict__ flags,
    const int* __restrict__ batch, int N, float* __restrict__ sums)
{
    int r0 = blockIdx.x * 128;
    if (r0 >= N) return;
    int r1 = min(r0 + 128, N);
    int t = threadIdx.x;               // column
    int f32 = flags[0];
    float m  = S[t] * invM;
    float v  = Q[t] * invM - m * m;
    float sc = ldf(g, t, f32) * rsqrtf(v + 1e-5f);
    float sh = ldf(be, t, f32) - m * sc;
    int stride = flags[2] ? 2 : 1;
    float acc = 0.f;
    int curg = batch[r0 * stride];
    for (int r = r0; r < r1; r++){
        int gg = batch[r * stride];
        if (gg != curg){
            atomicAdd(&sums[curg * HDIM + t], acc);
            acc = 0.f; curg = gg;
        }
        float hv = bf2f(H[(size_t)r * HDIM + t]) * sc + sh;
        hv = (hv < 0.f) ? 0.f : hv;
        hv += bf2f(res[(size_t)r * HDIM + t]);
        acc += hv;
    }
    atomicAdd(&sums[curg * HDIM + t], acc);
}

// ---------------- FC head (fused pool finalize) ----------------
__global__ __launch_bounds__(256) void head_kernel(const float* __restrict__ sums,
                                                   const int* __restrict__ batch, int N,
                                                   const void* __restrict__ fcW1,
                                                   const void* __restrict__ fcb1,
                                                   const void* __restrict__ fcW2,
                                                   const void* __restrict__ fcb2,
                                                   void* __restrict__ out,
                                                   const int* __restrict__ flags){
    __shared__ float sp[256];
    __shared__ float red[256];
    __shared__ int scnt;
    int g = blockIdx.x, j = threadIdx.x;
    int f32 = flags[0];
    int stride = flags[2] ? 2 : 1;
    if (j == 0){
        int lo = 0, hi = N;
        while (lo < hi){ int mid = (lo + hi) >> 1; if (batch[mid * stride] < g) lo = mid + 1; else hi = mid; }
        int a = lo;
        lo = 0; hi = N;
        while (lo < hi){ int mid = (lo + hi) >> 1; if (batch[mid * stride] < g + 1) lo = mid + 1; else hi = mid; }
        scnt = lo - a;
    }
    __syncthreads();
    sp[j] = sums[g * HDIM + j] / (float)max(scnt, 1);
    __syncthreads();
    float acc = ldf(fcb1, j, f32);
    for (int k = 0; k < HDIM; k++) acc += sp[k] * ldf(fcW1, k * HDIM + j, f32);
    acc = (acc < 0.f) ? 0.f : acc;
    red[j] = acc * ldf(fcW2, j, f32);
    __syncthreads();
    for (int s = 128; s > 0; s >>= 1){
        if (j < s) red[j] += red[j + s];
        __syncthreads();
    }
    if (j == 0){
        float r = red[0] + ldf(fcb2, 0, f32);
        if (f32) ((float*)out)[g] = r;
        else     ((unsigned short*)out)[g] = f2bf(r);
    }
}

extern "C" void kernel_launch(void* const* d_in, const int* in_sizes, int n_in,
                              void* d_out, int out_size, void* d_ws, size_t ws_size,
                              hipStream_t stream)
{
    const unsigned short* x    = (const unsigned short*)d_in[0];
    const int*            ei   = (const int*)d_in[1];
    const int*            batch= (const int*)d_in[2];
    const void* W1   = d_in[4];
    const void* b1   = d_in[5];
    const void* W2   = d_in[6];
    const void* b2   = d_in[7];
    const void* W3   = d_in[8];
    const void* b3   = d_in[9];
    const void* g1   = d_in[10];
    const void* be1  = d_in[11];
    const void* g2   = d_in[12];
    const void* be2  = d_in[13];
    const void* g3   = d_in[14];
    const void* be3  = d_in[15];
    const void* fcW1 = d_in[16];
    const void* fcb1 = d_in[17];
    const void* fcW2 = d_in[18];
    const void* fcb2 = d_in[19];

    const int N = in_sizes[0] / 128;   // 50000
    const int E = in_sizes[1] / 2;     // 800000
    const int D = 128;

    // ---- workspace layout (~55.6 MB) ----
    char* p = (char*)d_ws;
    int*   deg     = (int*)p;   p += (size_t)N * 4;
    int*   fillc   = (int*)p;   p += (size_t)N * 4;
    float* stats   = (float*)p; p += 6 * 256 * 4;            // S0 Q0 S1 Q1 S2 Q2
    float* poolsum = (float*)p; p += NGRAPH * HDIM * 4;      // zeroed
    size_t zbytes  = (size_t)(p - (char*)d_ws);
    int*   flags   = (int*)p;   p += 16 * 4;
    int*   bsums   = (int*)p;   p += 256 * 4;
    int*   rowptr  = (int*)p;   p += ((size_t)N + 4) * 4;
    int*   csr     = (int*)p;   p += (size_t)E * 4;
    unsigned short* Wt1 = (unsigned short*)p; p += 256 * 128 * 2;
    unsigned short* Wt2 = (unsigned short*)p; p += 256 * 256 * 2;
    unsigned short* Wt3 = (unsigned short*)p; p += 256 * 256 * 2;
    unsigned short* B1  = (unsigned short*)p; p += (size_t)N * HDIM * 2;
    unsigned short* B2  = (unsigned short*)p; p += (size_t)N * HDIM * 2;
    unsigned short* Xc  = B1;                                // Xc dead before B1 born

    float* S0 = stats + 0 * 256; float* Q0 = stats + 1 * 256;
    float* S1 = stats + 2 * 256; float* Q1 = stats + 3 * 256;
    float* S2 = stats + 4 * 256; float* Q2 = stats + 5 * 256;

    const int nbN = (N + 255) / 256;
    const int nbE = (E + 255) / 256;
    const int gM  = (N + 127) / 128;
    const float invM = 1.0f / (float)N;
    const int total8 = N * HDIM / 8;
    const int zn = (int)(zbytes / 4);
    const int nx = N * D;

    detect_kernel<<<1, 64, 0, stream>>>(x, ei, batch, E, N, flags);
    zero_kernel<<<(zn + 255) / 256, 256, 0, stream>>>((int*)d_ws, zn);

    // CSR build
    hist_kernel<<<nbE, 256, 0, stream>>>(ei, E, N, flags, deg);
    scan1_kernel<<<nbN, 256, 0, stream>>>(deg, N, rowptr, bsums);
    scan2_kernel<<<1, 256, 0, stream>>>(bsums, nbN);
    scan3_kernel<<<nbN, 256, 0, stream>>>(deg, N, E, rowptr, bsums);
    fill_kernel<<<nbE, 256, 0, stream>>>(ei, E, N, flags, rowptr, fillc, csr);

    // canonicalize weights + x
    transpose_kernel<<<(128 * 256) / 256, 256, 0, stream>>>(W1, Wt1, 128, 256, flags);
    transpose_kernel<<<(256 * 256) / 256, 256, 0, stream>>>(W2, Wt2, 256, 256, flags);
    transpose_kernel<<<(256 * 256) / 256, 256, 0, stream>>>(W3, Wt3, 256, 256, flags);
    cvt_kernel<<<(nx + 255) / 256, 256, 0, stream>>>(x, Xc, nx, flags);

    // ---- Layer 1 ----
    agg_vec<128><<<(N + 15) / 16, 256, 0, stream>>>(Xc, D, rowptr, csr, B2, HDIM, N);
    gemm_inplace<<<gM, 256, 0, stream>>>(B2, Wt1, b1, N, D, flags, S0, Q0);
    bnrelu_kernel<<<(total8 + 255) / 256, 256, 0, stream>>>(
        B2, S0, Q0, g1, be1, invM, flags, (const unsigned short*)nullptr, B1, total8);

    // ---- Layer 2 ----
    agg_vec<256><<<(N + 7) / 8, 256, 0, stream>>>(B1, HDIM, rowptr, csr, B2, HDIM, N);
    gemm_inplace<<<gM, 256, 0, stream>>>(B2, Wt2, b2, N, HDIM, flags, S1, Q1);
    bnrelu_kernel<<<(total8 + 255) / 256, 256, 0, stream>>>(
        B2, S1, Q1, g2, be2, invM, flags, B1, B1, total8);

    // ---- Layer 3 (bnrelu fused with pooling; x3 never materialized) ----
    agg_vec<256><<<(N + 7) / 8, 256, 0, stream>>>(B1, HDIM, rowptr, csr, B2, HDIM, N);
    gemm_inplace<<<gM, 256, 0, stream>>>(B2, Wt3, b3, N, HDIM, flags, S2, Q2);
    bnrelu_pool_kernel<<<gM, 256, 0, stream>>>(
        B2, B1, S2, Q2, g3, be3, invM, flags, batch, N, poolsum);

    // ---- Head (fused pool finalize) ----
    head_kernel<<<NGRAPH, 256, 0, stream>>>(poolsum, batch, N, fcW1, fcb1, fcW2, fcb2, d_out, flags);

    (void)n_in; (void)out_size; (void)ws_size;
}